// Round 4
// baseline (649.731 us; speedup 1.0000x reference)
//
#include <hip/hip_runtime.h>

typedef __attribute__((ext_vector_type(8))) short s8v;
typedef __attribute__((ext_vector_type(4))) short s4v;
typedef __attribute__((ext_vector_type(4))) float f4v;

#define MFMA __builtin_amdgcn_mfma_f32_16x16x32_bf16

__device__ __forceinline__ float b2f(unsigned short b) {
  union { unsigned u; float f; } x; x.u = ((unsigned)b) << 16; return x.f;
}
__device__ __forceinline__ unsigned short f2b(float f) {
  union { float f; unsigned u; } x; x.f = f;
  unsigned r = x.u + 0x7fffu + ((x.u >> 16) & 1u);
  return (unsigned short)(r >> 16);
}
__device__ __forceinline__ void gl_lds16(const void* g, void* l) {
  __builtin_amdgcn_global_load_lds(
      (const __attribute__((address_space(1))) unsigned int*)g,
      (__attribute__((address_space(3))) unsigned int*)l, 16, 0, 0);
}

// ---------------- column-norm (sum of squares over rows) ----------------
__global__ void colsq(const float* __restrict__ W, float* __restrict__ out, int K) {
  int j = blockIdx.x * 256 + threadIdx.x;
  const float* p = W + (long)(blockIdx.y * 64) * K + j;
  float s = 0.f;
#pragma unroll 4
  for (int n = 0; n < 64; ++n) { float v = p[(long)n * K]; s += v * v; }
  atomicAdd(&out[j], s);
}

// ---------------- weight convert: bf16(W * rsqrt(colsum)) ----------------
__global__ void convw(const float* __restrict__ src, const float* __restrict__ cs,
                      unsigned short* __restrict__ dst, int Kmask) {
  long idx = ((long)blockIdx.x * 256 + threadIdx.x) << 2;
  float4 v = *(const float4*)(src + idx);
  int j = (int)(idx & (long)Kmask);
  s4v o;
  o[0] = (short)f2b(v.x * rsqrtf(cs[j]));
  o[1] = (short)f2b(v.y * rsqrtf(cs[j + 1]));
  o[2] = (short)f2b(v.z * rsqrtf(cs[j + 2]));
  o[3] = (short)f2b(v.w * rsqrtf(cs[j + 3]));
  *(s4v*)(dst + idx) = o;
}

__global__ void castf2b(const float* __restrict__ src, unsigned short* __restrict__ dst) {
  long idx = ((long)blockIdx.x * 256 + threadIdx.x) << 2;
  float4 v = *(const float4*)(src + idx);
  s4v o;
  o[0] = (short)f2b(v.x); o[1] = (short)f2b(v.y);
  o[2] = (short)f2b(v.z); o[3] = (short)f2b(v.w);
  *(s4v*)(dst + idx) = o;
}

// ---------------- 128x128 bf16 NT GEMM, 4-deep pipelined: C[m,n] = sum_k A[m,k]B[n,k] ----------------
__global__ __launch_bounds__(256) void gemm_bt(
    const unsigned short* __restrict__ A, const unsigned short* __restrict__ B,
    unsigned short* __restrict__ Cout, int K, int ldc) {
  __shared__ unsigned short smem[32768];  // 64 KB: 4 bufs x (A 8KB | B 8KB)
  const int tid = threadIdx.x, lane = tid & 63, w = tid >> 6;
  const int quad = lane >> 4, lq = lane & 15;
  const int wy = w >> 1, wx = w & 1;
  const int m0 = blockIdx.y << 7, n0 = blockIdx.x << 7;

  const int trow = tid >> 2;
  const int cb = ((tid & 3) ^ ((tid >> 3) & 3)) << 3;
  const unsigned short* Ag0 = A + (long)(m0 + trow) * K + cb;
  const unsigned short* Ag1 = A + (long)(m0 + 64 + trow) * K + cb;
  const unsigned short* Bg0 = B + (long)(n0 + trow) * K + cb;
  const unsigned short* Bg1 = B + (long)(n0 + 64 + trow) * K + cb;
  unsigned short* l0 = smem + (tid << 3);

  const int swz = ((lq >> 1) & 3) << 4;
  const int aoff = (wy * 64 + lq) * 64 + ((quad << 4) ^ swz);
  const int boff = 8192 + (wx * 64 + lq) * 64 + ((quad << 4) ^ swz);

  f4v acc[4][4];
  f4v zero = {0.f, 0.f, 0.f, 0.f};
#pragma unroll
  for (int i = 0; i < 4; ++i)
#pragma unroll
    for (int j = 0; j < 4; ++j) acc[i][j] = zero;

  auto stage = [&](int T) {
    const int bo = (T & 3) << 13;
    const int col = T << 5;
    gl_lds16(Ag0 + col, l0 + bo);
    gl_lds16(Ag1 + col, l0 + bo + 2048);
    gl_lds16(Bg0 + col, l0 + bo + 4096);
    gl_lds16(Bg1 + col, l0 + bo + 6144);
  };
  const char* sb = (const char*)smem;
  auto compute = [&](int kt) {
    const int bo = (kt & 3) << 14;
    s8v a[4], b[4];
#pragma unroll
    for (int i = 0; i < 4; ++i) a[i] = *(const s8v*)(sb + bo + aoff + i * 1024);
#pragma unroll
    for (int j = 0; j < 4; ++j) b[j] = *(const s8v*)(sb + bo + boff + j * 1024);
    __builtin_amdgcn_s_setprio(1);
#pragma unroll
    for (int i = 0; i < 4; ++i)
#pragma unroll
      for (int j = 0; j < 4; ++j)
        acc[i][j] = MFMA(a[i], b[j], acc[i][j], 0, 0, 0);
    __builtin_amdgcn_s_setprio(0);
  };

  const int nt = K >> 5;
  stage(0); stage(1); stage(2);
  for (int kt = 0; kt < nt - 2; ++kt) {
    asm volatile("s_waitcnt vmcnt(8)" ::: "memory");
    __builtin_amdgcn_s_barrier();
    asm volatile("" ::: "memory");
    if (kt < nt - 3) stage(kt + 3);
    compute(kt);
  }
  asm volatile("s_waitcnt vmcnt(4)" ::: "memory");
  __builtin_amdgcn_s_barrier();
  asm volatile("" ::: "memory");
  compute(nt - 2);
  asm volatile("s_waitcnt vmcnt(0)" ::: "memory");
  __builtin_amdgcn_s_barrier();
  asm volatile("" ::: "memory");
  compute(nt - 1);

  __syncthreads();
#pragma unroll
  for (int i = 0; i < 4; ++i)
#pragma unroll
    for (int j = 0; j < 4; ++j)
#pragma unroll
      for (int r = 0; r < 4; ++r) {
        int row = wy * 64 + i * 16 + quad * 4 + r;
        int col = wx * 64 + j * 16 + lq;
        smem[row * 136 + col] = f2b(acc[i][j][r]);
      }
  __syncthreads();
#pragma unroll
  for (int it = 0; it < 8; ++it) {
    int row = it * 16 + (tid >> 4);
    int col = (tid & 15) << 3;
    s8v v = *(const s8v*)(smem + row * 136 + col);
    *(s8v*)(Cout + (long)(m0 + row) * ldc + n0 + col) = v;
  }
}

// ---------------- Wfc GEMM fused with SwiGLU: 256x256 tile, BK=64, 8-phase schedule ----------------
__global__ __launch_bounds__(512, 2) void gemm_fc(
    const unsigned short* __restrict__ A, const unsigned short* __restrict__ B,
    unsigned short* __restrict__ X, const float* __restrict__ suv) {
  __shared__ unsigned short smem[65536];  // 128 KB
  const int tid = threadIdx.x, lane = tid & 63, w = tid >> 6;
  const int quad = lane >> 4, lq = lane & 15;
  const int wy = w >> 2, wx = w & 3;
  const int bid = blockIdx.x;
  const int xr = bid & 7, xq = bid >> 3;  // XCD chunk, m-minor (B panel L2-reused 4x)
  const int m0 = ((xr << 2) | (xq & 3)) << 8;
  const int n0 = (xq >> 2) << 7;

  const int trow = tid >> 3;                       // 0..63
  const int scol = ((tid & 7) ^ (trow & 7)) << 3;  // bf16 col within 64
  const unsigned short* pA = A + (long)(m0 + trow) * 1024 + scol;
  const unsigned short* pB = B + (long)(n0 + trow) * 1024 + scol;
  unsigned short* ldst = smem + tid * 8;

  auto stA = [&](int tile, int half) {
    const int base = (tile & 1) * 32768 + half * 8192;
    const unsigned short* src = pA + (long)half * 131072 + (tile << 6);
    gl_lds16(src, ldst + base);
    gl_lds16(src + 65536, ldst + base + 4096);
  };
  auto stB = [&](int tile, int vh) {
    const int base = (tile & 1) * 32768 + 16384 + vh * 8192;
    const unsigned short* src = pB + (long)vh * 4194304 + (tile << 6);
    gl_lds16(src, ldst + base);
    gl_lds16(src + 65536, ldst + base + 4096);
  };

  const int rsw = (lq & 7) << 4;
  const int c0 = (quad * 16) ^ rsw;
  const int c1 = (64 + quad * 16) ^ rsw;
  const int aro = wy * 16384 + lq * 128;
  const int uro = 32768 + (wx * 32 + lq) * 128;
  const int vro = 49152 + (wx * 32 + lq) * 128;
  const char* sb = (const char*)smem;

  f4v aU[8][2], aV[8][2];
  f4v zero = {0.f, 0.f, 0.f, 0.f};
#pragma unroll
  for (int m = 0; m < 8; ++m)
#pragma unroll
    for (int j = 0; j < 2; ++j) { aU[m][j] = zero; aV[m][j] = zero; }

  s8v av[4][2], uf[2][2], vg[2][2];

  auto tile_phases = [&](int t, int bufB) {
    // ---------------- P0 ----------------
#pragma unroll
    for (int m = 0; m < 4; ++m) {
      av[m][0] = *(const s8v*)(sb + bufB + aro + m * 2048 + c0);
      av[m][1] = *(const s8v*)(sb + bufB + aro + m * 2048 + c1);
    }
#pragma unroll
    for (int j = 0; j < 2; ++j) {
      uf[j][0] = *(const s8v*)(sb + bufB + uro + j * 2048 + c0);
      uf[j][1] = *(const s8v*)(sb + bufB + uro + j * 2048 + c1);
    }
    if (t < 15) stA(t + 1, 1);
    __builtin_amdgcn_s_barrier();
    asm volatile("" ::: "memory");
    __builtin_amdgcn_s_setprio(1);
#pragma unroll
    for (int m = 0; m < 4; ++m)
#pragma unroll
      for (int j = 0; j < 2; ++j) {
        aU[m][j] = MFMA(av[m][0], uf[j][0], aU[m][j], 0, 0, 0);
        aU[m][j] = MFMA(av[m][1], uf[j][1], aU[m][j], 0, 0, 0);
      }
    __builtin_amdgcn_s_setprio(0);
    asm volatile("" ::: "memory");
    __builtin_amdgcn_s_barrier();
    asm volatile("" ::: "memory");
    // ---------------- P1 ----------------
#pragma unroll
    for (int j = 0; j < 2; ++j) {
      vg[j][0] = *(const s8v*)(sb + bufB + vro + j * 2048 + c0);
      vg[j][1] = *(const s8v*)(sb + bufB + vro + j * 2048 + c1);
    }
    if (t < 14) stB(t + 2, 0);
    __builtin_amdgcn_s_barrier();
    asm volatile("" ::: "memory");
    __builtin_amdgcn_s_setprio(1);
#pragma unroll
    for (int m = 0; m < 4; ++m)
#pragma unroll
      for (int j = 0; j < 2; ++j) {
        aV[m][j] = MFMA(av[m][0], vg[j][0], aV[m][j], 0, 0, 0);
        aV[m][j] = MFMA(av[m][1], vg[j][1], aV[m][j], 0, 0, 0);
      }
    __builtin_amdgcn_s_setprio(0);
    asm volatile("" ::: "memory");
    __builtin_amdgcn_s_barrier();
    asm volatile("" ::: "memory");
    // ---------------- P2 ----------------
#pragma unroll
    for (int m = 0; m < 4; ++m) {
      av[m][0] = *(const s8v*)(sb + bufB + aro + (m + 4) * 2048 + c0);
      av[m][1] = *(const s8v*)(sb + bufB + aro + (m + 4) * 2048 + c1);
    }
    if (t < 14) stB(t + 2, 1);
    __builtin_amdgcn_s_barrier();
    asm volatile("" ::: "memory");
    __builtin_amdgcn_s_setprio(1);
#pragma unroll
    for (int m = 0; m < 4; ++m)
#pragma unroll
      for (int j = 0; j < 2; ++j) {
        aU[m + 4][j] = MFMA(av[m][0], uf[j][0], aU[m + 4][j], 0, 0, 0);
        aU[m + 4][j] = MFMA(av[m][1], uf[j][1], aU[m + 4][j], 0, 0, 0);
      }
    __builtin_amdgcn_s_setprio(0);
    asm volatile("" ::: "memory");
    __builtin_amdgcn_s_barrier();
    asm volatile("" ::: "memory");
    // ---------------- P3 ----------------
    if (t < 14) stA(t + 2, 0);
    __builtin_amdgcn_s_barrier();
    asm volatile("" ::: "memory");
    __builtin_amdgcn_s_setprio(1);
#pragma unroll
    for (int m = 0; m < 4; ++m)
#pragma unroll
      for (int j = 0; j < 2; ++j) {
        aV[m + 4][j] = MFMA(av[m][0], vg[j][0], aV[m + 4][j], 0, 0, 0);
        aV[m + 4][j] = MFMA(av[m][1], vg[j][1], aV[m + 4][j], 0, 0, 0);
      }
    __builtin_amdgcn_s_setprio(0);
    if (t < 14) { asm volatile("s_waitcnt vmcnt(6)" ::: "memory"); }
    else if (t == 14) { asm volatile("s_waitcnt vmcnt(0)" ::: "memory"); }
    asm volatile("" ::: "memory");
    __builtin_amdgcn_s_barrier();
    asm volatile("" ::: "memory");
  };

  stB(0, 0); stB(0, 1); stA(0, 0); stA(0, 1);
  stB(1, 0); stB(1, 1); stA(1, 0);
  asm volatile("s_waitcnt vmcnt(6)" ::: "memory");
  __builtin_amdgcn_s_barrier();
  asm volatile("" ::: "memory");

  for (int tt = 0; tt < 8; ++tt) {
    tile_phases(tt * 2, 0);
    tile_phases(tt * 2 + 1, 65536);
  }

  float su[2], sv[2];
#pragma unroll
  for (int j = 0; j < 2; ++j) {
    su[j] = suv[n0 + wx * 32 + j * 16 + lq] * 32.f;
    sv[j] = suv[4096 + n0 + wx * 32 + j * 16 + lq] * 32.f;
  }
  __syncthreads();
#pragma unroll
  for (int m = 0; m < 8; ++m)
#pragma unroll
    for (int j = 0; j < 2; ++j)
#pragma unroll
      for (int r = 0; r < 4; ++r) {
        int row = wy * 128 + m * 16 + quad * 4 + r;
        int col = wx * 32 + j * 16 + lq;
        float uu = aU[m][j][r] * su[j];
        float vv = aV[m][j][r] * sv[j];
        float sig = 1.f / (1.f + __builtin_amdgcn_exp2f(vv * -1.44269504f));
        smem[row * 132 + col] = f2b(uu * vv * sig);
      }
  __syncthreads();
  {
    const int row = tid >> 1, half = tid & 1;
    unsigned short* dst = X + (long)(m0 + row) * 4096 + n0 + half * 64;
    const unsigned short* srcr = smem + row * 132 + half * 64;
#pragma unroll
    for (int s = 0; s < 8; ++s)
      *(s8v*)(dst + s * 8) = *(const s8v*)(srcr + s * 8);
  }
}

// ---------------- qkv post-process: justnorm q,k (in-place, *sqk*32), V -> Vt[BH,D,T] ----------------
__global__ __launch_bounds__(256) void qkv_norm(unsigned short* __restrict__ qkv,
                                                unsigned short* __restrict__ Vt,
                                                const float* __restrict__ sqk) {
  __shared__ unsigned short tl[64][72];
  const int tid = threadIdx.x;
  const int blk = blockIdx.x;
  const int tt = blk & 15, bh = blk >> 4, b = bh >> 4, h = bh & 15;
  const int t0 = tt << 6;
  const int r = tid >> 2, seg = tid & 3;
  float sc[16];
#pragma unroll
  for (int c = 0; c < 16; ++c) sc[c] = sqk[h * 64 + seg * 16 + c] * 32.f;
  for (int which = 0; which < 2; ++which) {
    unsigned short* p = qkv + (long)(b * 1024 + t0 + r) * 3072 + which * 1024 + h * 64 + seg * 16;
    s8v x0 = *(const s8v*)p, x1 = *(const s8v*)(p + 8);
    float ss = 0.f;
#pragma unroll
    for (int c = 0; c < 8; ++c) {
      float a = b2f((unsigned short)x0[c]), bb = b2f((unsigned short)x1[c]);
      ss += a * a + bb * bb;
    }
    ss += __shfl_xor(ss, 1, 64);
    ss += __shfl_xor(ss, 2, 64);
    float rn = rsqrtf(ss);
#pragma unroll
    for (int c = 0; c < 8; ++c) {
      x0[c] = (short)f2b(b2f((unsigned short)x0[c]) * rn * sc[c]);
      x1[c] = (short)f2b(b2f((unsigned short)x1[c]) * rn * sc[c + 8]);
    }
    *(s8v*)p = x0; *(s8v*)(p + 8) = x1;
  }
  {
    const unsigned short* p = qkv + (long)(b * 1024 + t0 + r) * 3072 + 2048 + h * 64 + seg * 16;
    s8v v0 = *(const s8v*)p, v1 = *(const s8v*)(p + 8);
#pragma unroll
    for (int c = 0; c < 8; ++c) {
      tl[seg * 16 + c][r] = (unsigned short)v0[c];
      tl[seg * 16 + 8 + c][r] = (unsigned short)v1[c];
    }
  }
  __syncthreads();
  {
    const int d = tid >> 2, part = tid & 3;
    s8v o0 = *(const s8v*)(&tl[d][part * 16]);
    s8v o1 = *(const s8v*)(&tl[d][part * 16 + 8]);
    unsigned short* q = Vt + (long)(bh * 64 + d) * 1024 + t0 + part * 16;
    *(s8v*)q = o0; *(s8v*)(q + 8) = o1;
  }
}

// ---------------- flash attention, K double-buffered (counted vmcnt), V direct-to-reg ----------------
// LDS 66KB: K ring 2x16KB | P 4x(32x136) at +16384. One raw s_barrier per K-tile.
// V panel (128KB/bh) is L2-resident & XCD-local (blocks sharing bh land on XCD bh%8):
// read V fragments straight to registers early in the tile; compiler's counted vmcnt
// covers the reg deps, K-stage gl_lds gated by the cheap vmcnt(0) at tile top
// (only K(t), issued one full tile earlier, is outstanding there).
__global__ __launch_bounds__(256) void attn(const unsigned short* __restrict__ qkv,
                                            const unsigned short* __restrict__ Vt,
                                            unsigned short* __restrict__ Y) {
  __shared__ unsigned short smem[33792];
  unsigned short* Plds = smem + 16384;
  const int tid = threadIdx.x, lane = tid & 63, w = tid >> 6;
  const int quad = lane >> 4, lq = lane & 15;
  const int bh = blockIdx.x, b = bh >> 4, h = bh & 15;
  const int qt = blockIdx.y;
  const int e0 = tid << 3;
  const int c_lo = e0 >> 10, row_s = (e0 & 1023) >> 3;

  s8v qf[2][2];
#pragma unroll
  for (int i = 0; i < 2; ++i)
#pragma unroll
    for (int ks = 0; ks < 2; ++ks) {
      int row = qt * 128 + w * 32 + i * 16 + lq;
      qf[i][ks] = *(const s8v*)(qkv + (long)(b * 1024 + row) * 3072 + h * 64 + ks * 32 + quad * 8);
    }

  f4v o[2][4];
  float lp[2][4];
  f4v zero = {0.f, 0.f, 0.f, 0.f};
#pragma unroll
  for (int i = 0; i < 2; ++i) {
#pragma unroll
    for (int nf = 0; nf < 4; ++nf) o[i][nf] = zero;
#pragma unroll
    for (int r = 0; r < 4; ++r) lp[i][r] = 0.f;
  }

  const unsigned short* Kg = qkv + (long)(b * 1024 + row_s) * 3072 + 1024 + h * 64 + (c_lo << 3);
  const unsigned short* Vrow = Vt + ((long)(bh * 64 + lq) * 1024) + quad * 8;  // + nf*16*1024 + t*128 + ks*32
  unsigned short* Pw = Plds + w * 4352;

  auto stageK = [&](int t) {
    unsigned short* dst = smem + (t & 1) * 8192 + e0;
    const unsigned short* src = Kg + (long)t * 393216;  // 128 rows * 3072
#pragma unroll
    for (int it = 0; it < 4; ++it)
      gl_lds16(src + it * 16, dst + it * 2048);
  };

  stageK(0);

  for (int t = 0; t < 8; ++t) {
    asm volatile("s_waitcnt vmcnt(0)" ::: "memory");  // K(t) (issued last tile) landed
    __builtin_amdgcn_s_barrier();
    asm volatile("" ::: "memory");
    // V fragments for this tile -> registers (consumed in PV, ~1200 cyc later)
    s8v vf[4][4];
#pragma unroll
    for (int nf = 0; nf < 4; ++nf)
#pragma unroll
      for (int ks = 0; ks < 4; ++ks)
        vf[nf][ks] = *(const s8v*)(Vrow + (long)nf * 16384 + t * 128 + ks * 32);
    if (t < 7) stageK(t + 1);

    const unsigned short* Kl = smem + (t & 1) * 8192;
    f4v s[2][8];
#pragma unroll
    for (int i = 0; i < 2; ++i)
#pragma unroll
      for (int j = 0; j < 8; ++j) s[i][j] = zero;
#pragma unroll
    for (int ks = 0; ks < 2; ++ks)
#pragma unroll
      for (int j = 0; j < 8; ++j) {
        s8v kf = *(const s8v*)(Kl + (ks * 4 + quad) * 1024 + (j * 16 + lq) * 8);
        s[0][j] = MFMA(qf[0][ks], kf, s[0][j], 0, 0, 0);
        s[1][j] = MFMA(qf[1][ks], kf, s[1][j], 0, 0, 0);
      }
#pragma unroll
    for (int i = 0; i < 2; ++i)
#pragma unroll
      for (int j = 0; j < 8; ++j)
#pragma unroll
        for (int r = 0; r < 4; ++r) {
          float p = __builtin_amdgcn_exp2f(s[i][j][r] * 11.5415603f - 11.5415603f);
          lp[i][r] += p;
          Pw[(i * 16 + quad * 4 + r) * 136 + j * 16 + lq] = f2b(p);
        }
    s8v pf[2][4];
#pragma unroll
    for (int i = 0; i < 2; ++i)
#pragma unroll
      for (int ks = 0; ks < 4; ++ks)
        pf[i][ks] = *(const s8v*)(Pw + (i * 16 + lq) * 136 + ks * 32 + quad * 8);
#pragma unroll
    for (int nf = 0; nf < 4; ++nf)
#pragma unroll
      for (int ks = 0; ks < 4; ++ks) {
        o[0][nf] = MFMA(pf[0][ks], vf[nf][ks], o[0][nf], 0, 0, 0);
        o[1][nf] = MFMA(pf[1][ks], vf[nf][ks], o[1][nf], 0, 0, 0);
      }
  }
#pragma unroll
  for (int i = 0; i < 2; ++i)
#pragma unroll
    for (int r = 0; r < 4; ++r) {
      float v = lp[i][r];
      v += __shfl_xor(v, 1, 64); v += __shfl_xor(v, 2, 64);
      v += __shfl_xor(v, 4, 64); v += __shfl_xor(v, 8, 64);
      lp[i][r] = 1.f / v;
    }
#pragma unroll
  for (int i = 0; i < 2; ++i)
#pragma unroll
    for (int nf = 0; nf < 4; ++nf)
#pragma unroll
      for (int r = 0; r < 4; ++r) {
        int row = qt * 128 + w * 32 + i * 16 + quad * 4 + r;
        Y[(long)(b * 1024 + row) * 1024 + h * 64 + nf * 16 + lq] = f2b(o[i][nf][r] * lp[i][r]);
      }
}

// ---------------- spherical-lerp residual: out = justnorm(A + |alpha*1.6|*(Bn - A)) ----------------
__global__ __launch_bounds__(256) void residual(
    const float* __restrict__ hin, const unsigned short* __restrict__ hbr,
    const float* __restrict__ alpha, float* __restrict__ outf,
    unsigned short* __restrict__ outb) {
  __shared__ float red[8];
  const int tid = threadIdx.x, lane = tid & 63, w = tid >> 6;
  const long base = (long)blockIdx.x * 1024;
  float hv[4], bvv[4];
  float s1 = 0.f, s2 = 0.f;
#pragma unroll
  for (int k = 0; k < 4; ++k) {
    int c = k * 256 + tid;
    hv[k] = hin[base + c];
    bvv[k] = b2f(hbr[base + c]);
    s1 += hv[k] * hv[k]; s2 += bvv[k] * bvv[k];
  }
#pragma unroll
  for (int m = 1; m < 64; m <<= 1) { s1 += __shfl_xor(s1, m, 64); s2 += __shfl_xor(s2, m, 64); }
  if (lane == 0) { red[w] = s1; red[4 + w] = s2; }
  __syncthreads();
  s1 = red[0] + red[1] + red[2] + red[3];
  s2 = red[4] + red[5] + red[6] + red[7];
  float rn1 = rsqrtf(s1), rn2 = rsqrtf(s2);
  float z[4], s3 = 0.f;
#pragma unroll
  for (int k = 0; k < 4; ++k) {
    int c = k * 256 + tid;
    float a = hv[k] * rn1;
    float lr = fabsf(alpha[c]) * 1.6f;
    float zz = a + lr * (bvv[k] * rn2 - a);
    z[k] = zz; s3 += zz * zz;
  }
#pragma unroll
  for (int m = 1; m < 64; m <<= 1) s3 += __shfl_xor(s3, m, 64);
  __syncthreads();
  if (lane == 0) red[w] = s3;
  __syncthreads();
  s3 = red[0] + red[1] + red[2] + red[3];
  float rn3 = rsqrtf(s3);
#pragma unroll
  for (int k = 0; k < 4; ++k) {
    int c = k * 256 + tid;
    float ov = z[k] * rn3;
    if (outf) outf[base + c] = ov;
    if (outb) outb[base + c] = f2b(ov);
  }
}

extern "C" void kernel_launch(void* const* d_in, const int* in_sizes, int n_in,
                              void* d_out, int out_size, void* d_ws, size_t ws_size,
                              hipStream_t stream) {
  const float* h   = (const float*)d_in[0];
  const float* Wq  = (const float*)d_in[1];
  const float* Wk  = (const float*)d_in[2];
  const float* Wv  = (const float*)d_in[3];
  const float* Wo  = (const float*)d_in[4];
  const float* Wfc = (const float*)d_in[5];
  const float* Wpj = (const float*)d_in[6];
  const float* sqk = (const float*)d_in[7];
  const float* suv = (const float*)d_in[8];
  const float* aat = (const float*)d_in[9];
  const float* aml = (const float*)d_in[10];
  float* out = (float*)d_out;  // reference output dtype is float32

  char* ws = (char*)d_ws;
  size_t off = 0;
  auto alloc = [&](size_t n) { char* p = ws + off; off += (n + 255) & ~(size_t)255; return p; };
  float* cs_q  = (float*)alloc(4096);
  float* cs_k  = (float*)alloc(4096);
  float* cs_v  = (float*)alloc(4096);
  float* cs_o  = (float*)alloc(4096);
  unsigned short* Wqkv_b = (unsigned short*)alloc(3ull * 1024 * 1024 * 2);
  unsigned short* Wo_b   = (unsigned short*)alloc(1024ull * 1024 * 2);
  unsigned short* Wfc_b  = (unsigned short*)alloc(8192ull * 1024 * 2);   // RAW (no col-norm)
  unsigned short* Wpj_b  = (unsigned short*)alloc(1024ull * 4096 * 2);   // RAW (no col-norm)
  unsigned short* slotC  = (unsigned short*)alloc(8192ull * 1024 * 2);   // h_b -> h_mlp
  unsigned short* slotD  = (unsigned short*)alloc(8192ull * 4096 * 2);   // qkv -> xmlp; hatt at +48MB
  unsigned short* slotE  = (unsigned short*)alloc(8192ull * 1024 * 2);   // Vt -> h2_b
  unsigned short* y_b    = (unsigned short*)alloc(8192ull * 1024 * 2);
  float*          h2_f   = (float*)alloc(8192ull * 1024 * 4);

  unsigned short* h_b    = slotC;
  unsigned short* hmlp_b = slotC;
  unsigned short* qkv_r  = slotD;
  unsigned short* xmlp   = slotD;
  unsigned short* hatt_b = slotD + 25165824;  // byte 48MB..64MB of slotD (qkv dead after attn)
  unsigned short* Vt     = slotE;
  unsigned short* h2_b   = slotE;

  hipMemsetAsync(ws, 0, 16384, stream);
  colsq<<<dim3(4, 16), 256, 0, stream>>>(Wq, cs_q, 1024);
  colsq<<<dim3(4, 16), 256, 0, stream>>>(Wk, cs_k, 1024);
  colsq<<<dim3(4, 16), 256, 0, stream>>>(Wv, cs_v, 1024);
  colsq<<<dim3(4, 16), 256, 0, stream>>>(Wo, cs_o, 1024);
  convw<<<1024, 256, 0, stream>>>(Wq, cs_q, Wqkv_b, 1023);
  convw<<<1024, 256, 0, stream>>>(Wk, cs_k, Wqkv_b + 1048576, 1023);
  convw<<<1024, 256, 0, stream>>>(Wv, cs_v, Wqkv_b + 2097152, 1023);
  convw<<<1024, 256, 0, stream>>>(Wo, cs_o, Wo_b, 1023);
  castf2b<<<8192, 256, 0, stream>>>(Wfc, Wfc_b);
  castf2b<<<4096, 256, 0, stream>>>(Wpj, Wpj_b);
  castf2b<<<8192, 256, 0, stream>>>(h, h_b);
  // qkv = h @ [Wq_n;Wk_n;Wv_n]^T
  gemm_bt<<<dim3(24, 64), 256, 0, stream>>>(h_b, Wqkv_b, qkv_r, 1024, 3072);
  qkv_norm<<<2048, 256, 0, stream>>>(qkv_r, Vt, sqk);
  attn<<<dim3(128, 8), 256, 0, stream>>>(qkv_r, Vt, y_b);
  // h_att = y @ Wo_n^T
  gemm_bt<<<dim3(8, 64), 256, 0, stream>>>(y_b, Wo_b, hatt_b, 1024, 1024);
  residual<<<8192, 256, 0, stream>>>(h, hatt_b, aat, h2_f, h2_b);
  // x_mlp = swiglu(h2 @ Wfc^T)  — 256x256-tile 8-phase pipelined kernel
  gemm_fc<<<1024, 512, 0, stream>>>(h2_b, Wfc_b, xmlp, suv);
  // h_mlp = x_mlp @ Wproj^T
  gemm_bt<<<dim3(8, 64), 256, 0, stream>>>(xmlp, Wpj_b, hmlp_b, 4096, 1024);
  // FINAL: write float32 to d_out
  residual<<<8192, 256, 0, stream>>>(h2_f, hmlp_b, aml, out, nullptr);
}

// Round 5
// 592.173 us; speedup vs baseline: 1.0972x; 1.0972x over previous
//
#include <hip/hip_runtime.h>

typedef __attribute__((ext_vector_type(8))) short s8v;
typedef __attribute__((ext_vector_type(4))) short s4v;
typedef __attribute__((ext_vector_type(4))) float f4v;

#define MFMA __builtin_amdgcn_mfma_f32_16x16x32_bf16

__device__ __forceinline__ float b2f(unsigned short b) {
  union { unsigned u; float f; } x; x.u = ((unsigned)b) << 16; return x.f;
}
__device__ __forceinline__ unsigned short f2b(float f) {
  union { float f; unsigned u; } x; x.f = f;
  unsigned r = x.u + 0x7fffu + ((x.u >> 16) & 1u);
  return (unsigned short)(r >> 16);
}
__device__ __forceinline__ void gl_lds16(const void* g, void* l) {
  __builtin_amdgcn_global_load_lds(
      (const __attribute__((address_space(1))) unsigned int*)g,
      (__attribute__((address_space(3))) unsigned int*)l, 16, 0, 0);
}

// ---------------- fused column-sumsq for Wq,Wk,Wv,Wo (one launch) ----------------
__global__ void colsq4(const float* __restrict__ Wq, const float* __restrict__ Wk,
                       const float* __restrict__ Wv, const float* __restrict__ Wo,
                       float* __restrict__ cs) {
  const int z = blockIdx.z;
  const float* W = (z == 0) ? Wq : (z == 1) ? Wk : (z == 2) ? Wv : Wo;
  int j = blockIdx.x * 256 + threadIdx.x;
  const float* p = W + (long)(blockIdx.y * 64) * 1024 + j;
  float s = 0.f;
#pragma unroll 4
  for (int n = 0; n < 64; ++n) { float v = p[(long)n * 1024]; s += v * v; }
  atomicAdd(&cs[z * 1024 + j], s);
}

// ---------------- fused weight convert for Wq,Wk,Wv,Wo (one launch) ----------------
// dst layout: Wqkv_b (3 matrices) then Wo_b contiguous => dst = base + y*1M elems.
__global__ void convw4(const float* __restrict__ Wq, const float* __restrict__ Wk,
                       const float* __restrict__ Wv, const float* __restrict__ Wo,
                       const float* __restrict__ cs, unsigned short* __restrict__ dst) {
  const int y = blockIdx.y;
  const float* src = (y == 0) ? Wq : (y == 1) ? Wk : (y == 2) ? Wv : Wo;
  long idx = ((long)blockIdx.x * 256 + threadIdx.x) << 2;
  float4 v = *(const float4*)(src + idx);
  const float* c = cs + y * 1024 + (int)(idx & 1023);
  s4v o;
  o[0] = (short)f2b(v.x * rsqrtf(c[0]));
  o[1] = (short)f2b(v.y * rsqrtf(c[1]));
  o[2] = (short)f2b(v.z * rsqrtf(c[2]));
  o[3] = (short)f2b(v.w * rsqrtf(c[3]));
  *(s4v*)(dst + (long)y * 1048576 + idx) = o;
}

// ---------------- fused f32->bf16 casts: Wfc | Wpj | h (one launch) ----------------
__global__ void cast3(const float* __restrict__ Wfc, const float* __restrict__ Wpj,
                      const float* __restrict__ h, unsigned short* __restrict__ Wfc_b,
                      unsigned short* __restrict__ Wpj_b, unsigned short* __restrict__ h_b) {
  int bid = blockIdx.x;
  const float* src; unsigned short* dst;
  if (bid < 8192) { src = Wfc; dst = Wfc_b; }
  else if (bid < 12288) { src = Wpj; dst = Wpj_b; bid -= 8192; }
  else { src = h; dst = h_b; bid -= 12288; }
  long idx = ((long)bid * 256 + threadIdx.x) << 2;
  float4 v = *(const float4*)(src + idx);
  s4v o;
  o[0] = (short)f2b(v.x); o[1] = (short)f2b(v.y);
  o[2] = (short)f2b(v.z); o[3] = (short)f2b(v.w);
  *(s4v*)(dst + idx) = o;
}

// ---------------- 128x128 bf16 NT GEMM, 4-deep pipelined: C[m,n] = sum_k A[m,k]B[n,k] ----------------
__global__ __launch_bounds__(256) void gemm_bt(
    const unsigned short* __restrict__ A, const unsigned short* __restrict__ B,
    unsigned short* __restrict__ Cout, int K, int ldc) {
  __shared__ unsigned short smem[32768];  // 64 KB: 4 bufs x (A 8KB | B 8KB)
  const int tid = threadIdx.x, lane = tid & 63, w = tid >> 6;
  const int quad = lane >> 4, lq = lane & 15;
  const int wy = w >> 1, wx = w & 1;
  const int m0 = blockIdx.y << 7, n0 = blockIdx.x << 7;

  const int trow = tid >> 2;
  const int cb = ((tid & 3) ^ ((tid >> 3) & 3)) << 3;
  const unsigned short* Ag0 = A + (long)(m0 + trow) * K + cb;
  const unsigned short* Ag1 = A + (long)(m0 + 64 + trow) * K + cb;
  const unsigned short* Bg0 = B + (long)(n0 + trow) * K + cb;
  const unsigned short* Bg1 = B + (long)(n0 + 64 + trow) * K + cb;
  unsigned short* l0 = smem + (tid << 3);

  const int swz = ((lq >> 1) & 3) << 4;
  const int aoff = (wy * 64 + lq) * 64 + ((quad << 4) ^ swz);
  const int boff = 8192 + (wx * 64 + lq) * 64 + ((quad << 4) ^ swz);

  f4v acc[4][4];
  f4v zero = {0.f, 0.f, 0.f, 0.f};
#pragma unroll
  for (int i = 0; i < 4; ++i)
#pragma unroll
    for (int j = 0; j < 4; ++j) acc[i][j] = zero;

  auto stage = [&](int T) {
    const int bo = (T & 3) << 13;
    const int col = T << 5;
    gl_lds16(Ag0 + col, l0 + bo);
    gl_lds16(Ag1 + col, l0 + bo + 2048);
    gl_lds16(Bg0 + col, l0 + bo + 4096);
    gl_lds16(Bg1 + col, l0 + bo + 6144);
  };
  const char* sb = (const char*)smem;
  auto compute = [&](int kt) {
    const int bo = (kt & 3) << 14;
    s8v a[4], b[4];
#pragma unroll
    for (int i = 0; i < 4; ++i) a[i] = *(const s8v*)(sb + bo + aoff + i * 1024);
#pragma unroll
    for (int j = 0; j < 4; ++j) b[j] = *(const s8v*)(sb + bo + boff + j * 1024);
    __builtin_amdgcn_s_setprio(1);
#pragma unroll
    for (int i = 0; i < 4; ++i)
#pragma unroll
      for (int j = 0; j < 4; ++j)
        acc[i][j] = MFMA(a[i], b[j], acc[i][j], 0, 0, 0);
    __builtin_amdgcn_s_setprio(0);
  };

  const int nt = K >> 5;
  stage(0); stage(1); stage(2);
  for (int kt = 0; kt < nt - 2; ++kt) {
    asm volatile("s_waitcnt vmcnt(8)" ::: "memory");
    __builtin_amdgcn_s_barrier();
    asm volatile("" ::: "memory");
    if (kt < nt - 3) stage(kt + 3);
    compute(kt);
  }
  asm volatile("s_waitcnt vmcnt(4)" ::: "memory");
  __builtin_amdgcn_s_barrier();
  asm volatile("" ::: "memory");
  compute(nt - 2);
  asm volatile("s_waitcnt vmcnt(0)" ::: "memory");
  __builtin_amdgcn_s_barrier();
  asm volatile("" ::: "memory");
  compute(nt - 1);

  __syncthreads();
#pragma unroll
  for (int i = 0; i < 4; ++i)
#pragma unroll
    for (int j = 0; j < 4; ++j)
#pragma unroll
      for (int r = 0; r < 4; ++r) {
        int row = wy * 64 + i * 16 + quad * 4 + r;
        int col = wx * 64 + j * 16 + lq;
        smem[row * 136 + col] = f2b(acc[i][j][r]);
      }
  __syncthreads();
#pragma unroll
  for (int it = 0; it < 8; ++it) {
    int row = it * 16 + (tid >> 4);
    int col = (tid & 15) << 3;
    s8v v = *(const s8v*)(smem + row * 136 + col);
    *(s8v*)(Cout + (long)(m0 + row) * ldc + n0 + col) = v;
  }
}

// ---------------- qkv GEMM with FUSED q/k justnorm (*sqk*32) and V->Vt transpose ----------------
// Same pipelined K-loop as gemm_bt (K=1024, ldc=3072). Epilogue:
//  n0<2048 (q,k): each block's 128-col tile holds complete 64-dim heads (head==wx half);
//    rsqrt(sum acc^2 over 64 cols) via 4 shfl_xor (lq group) on the f32 acc, scale, write.
//  n0>=2048 (v): acc -> LDS [col][row] (4 consecutive rows/lane = 1 packed b64 write,
//    free transpose), then coalesced copy-out to Vt[bh*64+d][t]. qkv_r v-third never written.
// sqk loads AFTER the K-loop (stray global loads would corrupt the counted vmcnt).
__global__ __launch_bounds__(256) void gemm_qkv(
    const unsigned short* __restrict__ A, const unsigned short* __restrict__ B,
    unsigned short* __restrict__ Cout, unsigned short* __restrict__ Vt,
    const float* __restrict__ sqk) {
  __shared__ unsigned short smem[32768];
  const int tid = threadIdx.x, lane = tid & 63, w = tid >> 6;
  const int quad = lane >> 4, lq = lane & 15;
  const int wy = w >> 1, wx = w & 1;
  const int m0 = blockIdx.y << 7, n0 = blockIdx.x << 7;
  const int K = 1024;

  const int trow = tid >> 2;
  const int cb = ((tid & 3) ^ ((tid >> 3) & 3)) << 3;
  const unsigned short* Ag0 = A + (long)(m0 + trow) * K + cb;
  const unsigned short* Ag1 = A + (long)(m0 + 64 + trow) * K + cb;
  const unsigned short* Bg0 = B + (long)(n0 + trow) * K + cb;
  const unsigned short* Bg1 = B + (long)(n0 + 64 + trow) * K + cb;
  unsigned short* l0 = smem + (tid << 3);

  const int swz = ((lq >> 1) & 3) << 4;
  const int aoff = (wy * 64 + lq) * 64 + ((quad << 4) ^ swz);
  const int boff = 8192 + (wx * 64 + lq) * 64 + ((quad << 4) ^ swz);

  f4v acc[4][4];
  f4v zero = {0.f, 0.f, 0.f, 0.f};
#pragma unroll
  for (int i = 0; i < 4; ++i)
#pragma unroll
    for (int j = 0; j < 4; ++j) acc[i][j] = zero;

  auto stage = [&](int T) {
    const int bo = (T & 3) << 13;
    const int col = T << 5;
    gl_lds16(Ag0 + col, l0 + bo);
    gl_lds16(Ag1 + col, l0 + bo + 2048);
    gl_lds16(Bg0 + col, l0 + bo + 4096);
    gl_lds16(Bg1 + col, l0 + bo + 6144);
  };
  const char* sb = (const char*)smem;
  auto compute = [&](int kt) {
    const int bo = (kt & 3) << 14;
    s8v a[4], b[4];
#pragma unroll
    for (int i = 0; i < 4; ++i) a[i] = *(const s8v*)(sb + bo + aoff + i * 1024);
#pragma unroll
    for (int j = 0; j < 4; ++j) b[j] = *(const s8v*)(sb + bo + boff + j * 1024);
    __builtin_amdgcn_s_setprio(1);
#pragma unroll
    for (int i = 0; i < 4; ++i)
#pragma unroll
      for (int j = 0; j < 4; ++j)
        acc[i][j] = MFMA(a[i], b[j], acc[i][j], 0, 0, 0);
    __builtin_amdgcn_s_setprio(0);
  };

  stage(0); stage(1); stage(2);
  for (int kt = 0; kt < 30; ++kt) {
    asm volatile("s_waitcnt vmcnt(8)" ::: "memory");
    __builtin_amdgcn_s_barrier();
    asm volatile("" ::: "memory");
    if (kt < 29) stage(kt + 3);
    compute(kt);
  }
  asm volatile("s_waitcnt vmcnt(4)" ::: "memory");
  __builtin_amdgcn_s_barrier();
  asm volatile("" ::: "memory");
  compute(30);
  asm volatile("s_waitcnt vmcnt(0)" ::: "memory");
  __builtin_amdgcn_s_barrier();
  asm volatile("" ::: "memory");
  compute(31);

  if (n0 < 2048) {
    // ---- q/k: fused per-head justnorm * sqk*32 on f32 acc ----
    float sc[4];
#pragma unroll
    for (int j = 0; j < 4; ++j)
      sc[j] = sqk[(n0 + wx * 64 + j * 16 + lq) & 1023] * 32.f;
#pragma unroll
    for (int i = 0; i < 4; ++i)
#pragma unroll
      for (int r = 0; r < 4; ++r) {
        float ss = 0.f;
#pragma unroll
        for (int j = 0; j < 4; ++j) ss += acc[i][j][r] * acc[i][j][r];
        ss += __shfl_xor(ss, 1, 64); ss += __shfl_xor(ss, 2, 64);
        ss += __shfl_xor(ss, 4, 64); ss += __shfl_xor(ss, 8, 64);
        float rn = rsqrtf(ss);
#pragma unroll
        for (int j = 0; j < 4; ++j) acc[i][j][r] *= rn * sc[j];
      }
    __syncthreads();
#pragma unroll
    for (int i = 0; i < 4; ++i)
#pragma unroll
      for (int j = 0; j < 4; ++j)
#pragma unroll
        for (int r = 0; r < 4; ++r) {
          int row = wy * 64 + i * 16 + quad * 4 + r;
          int col = wx * 64 + j * 16 + lq;
          smem[row * 136 + col] = f2b(acc[i][j][r]);
        }
    __syncthreads();
#pragma unroll
    for (int it = 0; it < 8; ++it) {
      int row = it * 16 + (tid >> 4);
      int col = (tid & 15) << 3;
      s8v v = *(const s8v*)(smem + row * 136 + col);
      *(s8v*)(Cout + (long)(m0 + row) * 3072 + n0 + col) = v;
    }
  } else {
    // ---- v: transpose via LDS [col][row], write Vt[bh*64+d][t] ----
    __syncthreads();
#pragma unroll
    for (int i = 0; i < 4; ++i)
#pragma unroll
      for (int j = 0; j < 4; ++j) {
        int col = wx * 64 + j * 16 + lq;
        int rowb = wy * 64 + i * 16 + quad * 4;
        s4v pk;
#pragma unroll
        for (int r = 0; r < 4; ++r) pk[r] = (short)f2b(acc[i][j][r]);
        *(s4v*)(smem + col * 136 + rowb) = pk;
      }
    __syncthreads();
    {
      const int c = tid >> 1, half = tid & 1;
      const int f = (n0 - 2048) + c;
      const int bh = ((m0 >> 10) << 4) + (f >> 6);
      const int d = f & 63;
      unsigned short* dst = Vt + (long)(bh * 64 + d) * 1024 + (m0 & 1023) + half * 64;
      const unsigned short* src = smem + c * 136 + half * 64;
#pragma unroll
      for (int s = 0; s < 8; ++s)
        *(s8v*)(dst + s * 8) = *(const s8v*)(src + s * 8);
    }
  }
}

// ---------------- Wfc GEMM fused with SwiGLU: 256x256 tile, BK=64, 8-phase schedule ----------------
__global__ __launch_bounds__(512, 2) void gemm_fc(
    const unsigned short* __restrict__ A, const unsigned short* __restrict__ B,
    unsigned short* __restrict__ X, const float* __restrict__ suv) {
  __shared__ unsigned short smem[65536];  // 128 KB
  const int tid = threadIdx.x, lane = tid & 63, w = tid >> 6;
  const int quad = lane >> 4, lq = lane & 15;
  const int wy = w >> 2, wx = w & 3;
  const int bid = blockIdx.x;
  const int xr = bid & 7, xq = bid >> 3;  // XCD chunk, m-minor (B panel L2-reused 4x)
  const int m0 = ((xr << 2) | (xq & 3)) << 8;
  const int n0 = (xq >> 2) << 7;

  const int trow = tid >> 3;
  const int scol = ((tid & 7) ^ (trow & 7)) << 3;
  const unsigned short* pA = A + (long)(m0 + trow) * 1024 + scol;
  const unsigned short* pB = B + (long)(n0 + trow) * 1024 + scol;
  unsigned short* ldst = smem + tid * 8;

  auto stA = [&](int tile, int half) {
    const int base = (tile & 1) * 32768 + half * 8192;
    const unsigned short* src = pA + (long)half * 131072 + (tile << 6);
    gl_lds16(src, ldst + base);
    gl_lds16(src + 65536, ldst + base + 4096);
  };
  auto stB = [&](int tile, int vh) {
    const int base = (tile & 1) * 32768 + 16384 + vh * 8192;
    const unsigned short* src = pB + (long)vh * 4194304 + (tile << 6);
    gl_lds16(src, ldst + base);
    gl_lds16(src + 65536, ldst + base + 4096);
  };

  const int rsw = (lq & 7) << 4;
  const int c0 = (quad * 16) ^ rsw;
  const int c1 = (64 + quad * 16) ^ rsw;
  const int aro = wy * 16384 + lq * 128;
  const int uro = 32768 + (wx * 32 + lq) * 128;
  const int vro = 49152 + (wx * 32 + lq) * 128;
  const char* sb = (const char*)smem;

  f4v aU[8][2], aV[8][2];
  f4v zero = {0.f, 0.f, 0.f, 0.f};
#pragma unroll
  for (int m = 0; m < 8; ++m)
#pragma unroll
    for (int j = 0; j < 2; ++j) { aU[m][j] = zero; aV[m][j] = zero; }

  s8v av[4][2], uf[2][2], vg[2][2];

  auto tile_phases = [&](int t, int bufB) {
    // ---------------- P0 ----------------
#pragma unroll
    for (int m = 0; m < 4; ++m) {
      av[m][0] = *(const s8v*)(sb + bufB + aro + m * 2048 + c0);
      av[m][1] = *(const s8v*)(sb + bufB + aro + m * 2048 + c1);
    }
#pragma unroll
    for (int j = 0; j < 2; ++j) {
      uf[j][0] = *(const s8v*)(sb + bufB + uro + j * 2048 + c0);
      uf[j][1] = *(const s8v*)(sb + bufB + uro + j * 2048 + c1);
    }
    if (t < 15) stA(t + 1, 1);
    __builtin_amdgcn_s_barrier();
    asm volatile("" ::: "memory");
    __builtin_amdgcn_s_setprio(1);
#pragma unroll
    for (int m = 0; m < 4; ++m)
#pragma unroll
      for (int j = 0; j < 2; ++j) {
        aU[m][j] = MFMA(av[m][0], uf[j][0], aU[m][j], 0, 0, 0);
        aU[m][j] = MFMA(av[m][1], uf[j][1], aU[m][j], 0, 0, 0);
      }
    __builtin_amdgcn_s_setprio(0);
    asm volatile("" ::: "memory");
    __builtin_amdgcn_s_barrier();
    asm volatile("" ::: "memory");
    // ---------------- P1 ----------------
#pragma unroll
    for (int j = 0; j < 2; ++j) {
      vg[j][0] = *(const s8v*)(sb + bufB + vro + j * 2048 + c0);
      vg[j][1] = *(const s8v*)(sb + bufB + vro + j * 2048 + c1);
    }
    if (t < 14) stB(t + 2, 0);
    __builtin_amdgcn_s_barrier();
    asm volatile("" ::: "memory");
    __builtin_amdgcn_s_setprio(1);
#pragma unroll
    for (int m = 0; m < 4; ++m)
#pragma unroll
      for (int j = 0; j < 2; ++j) {
        aV[m][j] = MFMA(av[m][0], vg[j][0], aV[m][j], 0, 0, 0);
        aV[m][j] = MFMA(av[m][1], vg[j][1], aV[m][j], 0, 0, 0);
      }
    __builtin_amdgcn_s_setprio(0);
    asm volatile("" ::: "memory");
    __builtin_amdgcn_s_barrier();
    asm volatile("" ::: "memory");
    // ---------------- P2 ----------------
#pragma unroll
    for (int m = 0; m < 4; ++m) {
      av[m][0] = *(const s8v*)(sb + bufB + aro + (m + 4) * 2048 + c0);
      av[m][1] = *(const s8v*)(sb + bufB + aro + (m + 4) * 2048 + c1);
    }
    if (t < 14) stB(t + 2, 1);
    __builtin_amdgcn_s_barrier();
    asm volatile("" ::: "memory");
    __builtin_amdgcn_s_setprio(1);
#pragma unroll
    for (int m = 0; m < 4; ++m)
#pragma unroll
      for (int j = 0; j < 2; ++j) {
        aU[m + 4][j] = MFMA(av[m][0], uf[j][0], aU[m + 4][j], 0, 0, 0);
        aU[m + 4][j] = MFMA(av[m][1], uf[j][1], aU[m + 4][j], 0, 0, 0);
      }
    __builtin_amdgcn_s_setprio(0);
    asm volatile("" ::: "memory");
    __builtin_amdgcn_s_barrier();
    asm volatile("" ::: "memory");
    // ---------------- P3 ----------------
    if (t < 14) stA(t + 2, 0);
    __builtin_amdgcn_s_barrier();
    asm volatile("" ::: "memory");
    __builtin_amdgcn_s_setprio(1);
#pragma unroll
    for (int m = 0; m < 4; ++m)
#pragma unroll
      for (int j = 0; j < 2; ++j) {
        aV[m + 4][j] = MFMA(av[m][0], vg[j][0], aV[m + 4][j], 0, 0, 0);
        aV[m + 4][j] = MFMA(av[m][1], vg[j][1], aV[m + 4][j], 0, 0, 0);
      }
    __builtin_amdgcn_s_setprio(0);
    if (t < 14) { asm volatile("s_waitcnt vmcnt(6)" ::: "memory"); }
    else if (t == 14) { asm volatile("s_waitcnt vmcnt(0)" ::: "memory"); }
    asm volatile("" ::: "memory");
    __builtin_amdgcn_s_barrier();
    asm volatile("" ::: "memory");
  };

  stB(0, 0); stB(0, 1); stA(0, 0); stA(0, 1);
  stB(1, 0); stB(1, 1); stA(1, 0);
  asm volatile("s_waitcnt vmcnt(6)" ::: "memory");
  __builtin_amdgcn_s_barrier();
  asm volatile("" ::: "memory");

  for (int tt = 0; tt < 8; ++tt) {
    tile_phases(tt * 2, 0);
    tile_phases(tt * 2 + 1, 65536);
  }

  float su[2], sv[2];
#pragma unroll
  for (int j = 0; j < 2; ++j) {
    su[j] = suv[n0 + wx * 32 + j * 16 + lq] * 32.f;
    sv[j] = suv[4096 + n0 + wx * 32 + j * 16 + lq] * 32.f;
  }
  __syncthreads();
#pragma unroll
  for (int m = 0; m < 8; ++m)
#pragma unroll
    for (int j = 0; j < 2; ++j)
#pragma unroll
      for (int r = 0; r < 4; ++r) {
        int row = wy * 128 + m * 16 + quad * 4 + r;
        int col = wx * 32 + j * 16 + lq;
        float uu = aU[m][j][r] * su[j];
        float vv = aV[m][j][r] * sv[j];
        float sig = 1.f / (1.f + __builtin_amdgcn_exp2f(vv * -1.44269504f));
        smem[row * 132 + col] = f2b(uu * vv * sig);
      }
  __syncthreads();
  {
    const int row = tid >> 1, half = tid & 1;
    unsigned short* dst = X + (long)(m0 + row) * 4096 + n0 + half * 64;
    const unsigned short* srcr = smem + row * 132 + half * 64;
#pragma unroll
    for (int s = 0; s < 8; ++s)
      *(s8v*)(dst + s * 8) = *(const s8v*)(srcr + s * 8);
  }
}

// ---------------- flash attention (non-causal, bounded logits -> no running max) ----------------
__global__ __launch_bounds__(256) void attn(const unsigned short* __restrict__ qkv,
                                            const unsigned short* __restrict__ Vt,
                                            unsigned short* __restrict__ Y) {
  __shared__ unsigned short smem[33792];
  unsigned short* Klds = smem;
  unsigned short* Vlds = smem + 8192;
  unsigned short* Plds = smem + 16384;
  const int tid = threadIdx.x, lane = tid & 63, w = tid >> 6;
  const int quad = lane >> 4, lq = lane & 15;
  const int bh = blockIdx.x, b = bh >> 4, h = bh & 15;
  const int qt = blockIdx.y;
  const int e0 = tid << 3;
  const int c_lo = e0 >> 10, row_s = (e0 & 1023) >> 3;
  const int vc_lo = e0 >> 9, vd = (e0 & 511) >> 3;

  s8v qf[2][2];
#pragma unroll
  for (int i = 0; i < 2; ++i)
#pragma unroll
    for (int ks = 0; ks < 2; ++ks) {
      int row = qt * 128 + w * 32 + i * 16 + lq;
      qf[i][ks] = *(const s8v*)(qkv + (long)(b * 1024 + row) * 3072 + h * 64 + ks * 32 + quad * 8);
    }

  f4v o[2][4];
  float lp[2][4];
  f4v zero = {0.f, 0.f, 0.f, 0.f};
#pragma unroll
  for (int i = 0; i < 2; ++i) {
#pragma unroll
    for (int nf = 0; nf < 4; ++nf) o[i][nf] = zero;
#pragma unroll
    for (int r = 0; r < 4; ++r) lp[i][r] = 0.f;
  }

  const unsigned short* Kg = qkv + (long)(b * 1024 + row_s) * 3072 + 1024 + h * 64 + (c_lo << 3);
  const unsigned short* Vg = Vt + (long)(bh * 64 + vd) * 1024 + (vc_lo << 3);
  unsigned short* Pw = Plds + w * 4352;

  for (int kt0 = 0; kt0 < 1024; kt0 += 128) {
    __syncthreads();
#pragma unroll
    for (int it = 0; it < 4; ++it) {
      gl_lds16(Kg + (long)kt0 * 3072 + it * 16, Klds + it * 2048 + e0);
      gl_lds16(Vg + kt0 + it * 32, Vlds + it * 2048 + e0);
    }
    __syncthreads();
    f4v s[2][8];
#pragma unroll
    for (int i = 0; i < 2; ++i)
#pragma unroll
      for (int j = 0; j < 8; ++j) s[i][j] = zero;
#pragma unroll
    for (int ks = 0; ks < 2; ++ks)
#pragma unroll
      for (int j = 0; j < 8; ++j) {
        s8v kf = *(const s8v*)(Klds + (ks * 4 + quad) * 1024 + (j * 16 + lq) * 8);
        s[0][j] = MFMA(qf[0][ks], kf, s[0][j], 0, 0, 0);
        s[1][j] = MFMA(qf[1][ks], kf, s[1][j], 0, 0, 0);
      }
#pragma unroll
    for (int i = 0; i < 2; ++i)
#pragma unroll
      for (int j = 0; j < 8; ++j)
#pragma unroll
        for (int r = 0; r < 4; ++r) {
          float p = __builtin_amdgcn_exp2f(s[i][j][r] * 11.5415603f - 11.5415603f);
          lp[i][r] += p;
          Pw[(i * 16 + quad * 4 + r) * 136 + j * 16 + lq] = f2b(p);
        }
    s8v pf[2][4];
#pragma unroll
    for (int i = 0; i < 2; ++i)
#pragma unroll
      for (int ks = 0; ks < 4; ++ks)
        pf[i][ks] = *(const s8v*)(Pw + (i * 16 + lq) * 136 + ks * 32 + quad * 8);
#pragma unroll
    for (int nf = 0; nf < 4; ++nf)
#pragma unroll
      for (int ks = 0; ks < 4; ++ks) {
        s8v vf = *(const s8v*)(Vlds + (ks * 4 + quad) * 512 + (nf * 16 + lq) * 8);
        o[0][nf] = MFMA(pf[0][ks], vf, o[0][nf], 0, 0, 0);
        o[1][nf] = MFMA(pf[1][ks], vf, o[1][nf], 0, 0, 0);
      }
  }
#pragma unroll
  for (int i = 0; i < 2; ++i)
#pragma unroll
    for (int r = 0; r < 4; ++r) {
      float v = lp[i][r];
      v += __shfl_xor(v, 1, 64); v += __shfl_xor(v, 2, 64);
      v += __shfl_xor(v, 4, 64); v += __shfl_xor(v, 8, 64);
      lp[i][r] = 1.f / v;
    }
#pragma unroll
  for (int i = 0; i < 2; ++i)
#pragma unroll
    for (int nf = 0; nf < 4; ++nf)
#pragma unroll
      for (int r = 0; r < 4; ++r) {
        int row = qt * 128 + w * 32 + i * 16 + quad * 4 + r;
        Y[(long)(b * 1024 + row) * 1024 + h * 64 + nf * 16 + lq] = f2b(o[i][nf][r] * lp[i][r]);
      }
}

// ---------------- spherical-lerp residual: out = justnorm(A + |alpha*1.6|*(Bn - A)) ----------------
__global__ __launch_bounds__(256) void residual(
    const float* __restrict__ hin, const unsigned short* __restrict__ hbr,
    const float* __restrict__ alpha, float* __restrict__ outf,
    unsigned short* __restrict__ outb) {
  __shared__ float red[8];
  const int tid = threadIdx.x, lane = tid & 63, w = tid >> 6;
  const long base = (long)blockIdx.x * 1024;
  float hv[4], bvv[4];
  float s1 = 0.f, s2 = 0.f;
#pragma unroll
  for (int k = 0; k < 4; ++k) {
    int c = k * 256 + tid;
    hv[k] = hin[base + c];
    bvv[k] = b2f(hbr[base + c]);
    s1 += hv[k] * hv[k]; s2 += bvv[k] * bvv[k];
  }
#pragma unroll
  for (int m = 1; m < 64; m <<= 1) { s1 += __shfl_xor(s1, m, 64); s2 += __shfl_xor(s2, m, 64); }
  if (lane == 0) { red[w] = s1; red[4 + w] = s2; }
  __syncthreads();
  s1 = red[0] + red[1] + red[2] + red[3];
  s2 = red[4] + red[5] + red[6] + red[7];
  float rn1 = rsqrtf(s1), rn2 = rsqrtf(s2);
  float z[4], s3 = 0.f;
#pragma unroll
  for (int k = 0; k < 4; ++k) {
    int c = k * 256 + tid;
    float a = hv[k] * rn1;
    float lr = fabsf(alpha[c]) * 1.6f;
    float zz = a + lr * (bvv[k] * rn2 - a);
    z[k] = zz; s3 += zz * zz;
  }
#pragma unroll
  for (int m = 1; m < 64; m <<= 1) s3 += __shfl_xor(s3, m, 64);
  __syncthreads();
  if (lane == 0) red[w] = s3;
  __syncthreads();
  s3 = red[0] + red[1] + red[2] + red[3];
  float rn3 = rsqrtf(s3);
#pragma unroll
  for (int k = 0; k < 4; ++k) {
    int c = k * 256 + tid;
    float ov = z[k] * rn3;
    if (outf) outf[base + c] = ov;
    if (outb) outb[base + c] = f2b(ov);
  }
}

extern "C" void kernel_launch(void* const* d_in, const int* in_sizes, int n_in,
                              void* d_out, int out_size, void* d_ws, size_t ws_size,
                              hipStream_t stream) {
  const float* h   = (const float*)d_in[0];
  const float* Wq  = (const float*)d_in[1];
  const float* Wk  = (const float*)d_in[2];
  const float* Wv  = (const float*)d_in[3];
  const float* Wo  = (const float*)d_in[4];
  const float* Wfc = (const float*)d_in[5];
  const float* Wpj = (const float*)d_in[6];
  const float* sqk = (const float*)d_in[7];
  const float* suv = (const float*)d_in[8];
  const float* aat = (const float*)d_in[9];
  const float* aml = (const float*)d_in[10];
  float* out = (float*)d_out;  // reference output dtype is float32

  char* ws = (char*)d_ws;
  size_t off = 0;
  auto alloc = [&](size_t n) { char* p = ws + off; off += (n + 255) & ~(size_t)255; return p; };
  float* cs4   = (float*)alloc(16384);  // 4 x 1024 f32, contiguous
  unsigned short* Wqkv_b = (unsigned short*)alloc(3ull * 1024 * 1024 * 2);
  unsigned short* Wo_b   = (unsigned short*)alloc(1024ull * 1024 * 2);   // == Wqkv_b + 3*1M elems
  unsigned short* Wfc_b  = (unsigned short*)alloc(8192ull * 1024 * 2);   // RAW (no col-norm)
  unsigned short* Wpj_b  = (unsigned short*)alloc(1024ull * 4096 * 2);   // RAW (no col-norm)
  unsigned short* slotC  = (unsigned short*)alloc(8192ull * 1024 * 2);   // h_b -> h_mlp
  unsigned short* slotD  = (unsigned short*)alloc(8192ull * 4096 * 2);   // qkv -> xmlp; hatt at +48MB
  unsigned short* slotE  = (unsigned short*)alloc(8192ull * 1024 * 2);   // Vt -> h2_b
  unsigned short* y_b    = (unsigned short*)alloc(8192ull * 1024 * 2);
  float*          h2_f   = (float*)alloc(8192ull * 1024 * 4);

  unsigned short* h_b    = slotC;
  unsigned short* hmlp_b = slotC;
  unsigned short* qkv_r  = slotD;
  unsigned short* xmlp   = slotD;
  unsigned short* hatt_b = slotD + 25165824;  // byte 48MB..64MB of slotD (qkv dead after attn)
  unsigned short* Vt     = slotE;
  unsigned short* h2_b   = slotE;

  hipMemsetAsync(ws, 0, 16384, stream);
  colsq4<<<dim3(4, 16, 4), 256, 0, stream>>>(Wq, Wk, Wv, Wo, cs4);
  convw4<<<dim3(1024, 4), 256, 0, stream>>>(Wq, Wk, Wv, Wo, cs4, Wqkv_b);
  cast3<<<20480, 256, 0, stream>>>(Wfc, Wpj, h, Wfc_b, Wpj_b, h_b);
  // qkv = h @ [Wq_n;Wk_n;Wv_n]^T with fused q/k justnorm*sqk and V->Vt transpose
  gemm_qkv<<<dim3(24, 64), 256, 0, stream>>>(h_b, Wqkv_b, qkv_r, Vt, sqk);
  attn<<<dim3(128, 8), 256, 0, stream>>>(qkv_r, Vt, y_b);
  // h_att = y @ Wo_n^T
  gemm_bt<<<dim3(8, 64), 256, 0, stream>>>(y_b, Wo_b, hatt_b, 1024, 1024);
  residual<<<8192, 256, 0, stream>>>(h, hatt_b, aat, h2_f, h2_b);
  // x_mlp = swiglu(h2 @ Wfc^T)  — 256x256-tile 8-phase pipelined kernel
  gemm_fc<<<1024, 512, 0, stream>>>(h2_b, Wfc_b, xmlp, suv);
  // h_mlp = x_mlp @ Wproj^T
  gemm_bt<<<dim3(8, 64), 256, 0, stream>>>(xmlp, Wpj_b, hmlp_b, 4096, 1024);
  // FINAL: write float32 to d_out
  residual<<<8192, 256, 0, stream>>>(h2_f, hmlp_b, aml, out, nullptr);
}